// Round 7
// baseline (478.427 us; speedup 1.0000x reference)
//
#include <hip/hip_runtime.h>
#include <math.h>

#define N_TOK 131072
#define DIM   64
#define QS    8
#define KS    1024

typedef _Float16 f16x8  __attribute__((ext_vector_type(8)));
typedef float    f32x4  __attribute__((ext_vector_type(4)));
typedef float    f32x16 __attribute__((ext_vector_type(16)));

#define RSCALE   2048.0f
#define RISCALE  4.8828125e-4f   // 2^-11

// split fp32 v into f16 limbs + scaled-hi: v ~= hi + lo*2^-11 ; hs = 2048*hi (exact)
#define SPLIT3(v, hi, lo, hs) { _Float16 _h = (_Float16)(v); (hi) = _h;        \
                                (lo) = (_Float16)(((v) - (float)_h) * RSCALE); \
                                (hs) = (_Float16)((float)_h * RSCALE); }

// ---- workspace layout G: 128 chunks, each 16640 B:
//   [0    .. 16383]  frag limbs for 32x32x16 A-operand: 16 sub-slots of 1KB
//                    sub-slot w = tile*8 + limb*4 + ksub  (tile:2, limb:{hi,lo}, ksub:4)
//   [16384.. 16639]  64 floats: -1024*||c||^2 seeds for the chunk's 64 codewords
// Chunk c covers stage q = c>>4, codewords (c&15)*64 .. +63.
#define CHUNK_B   16640
#define CHUNK_H   8320
#define DC2_OFF_H 8192

// ---- pre-pass 1: codebook -> f16 limbs in 32x32x16 MFMA A-fragment order.
// A layout: row(cw) = lane&31, k = ksub*16 + (lane>>5)*8 + j.
__global__ void conv_kernel(const float* __restrict__ cb, _Float16* __restrict__ G) {
    int t = blockIdx.x * blockDim.x + threadIdx.x;
    if (t >= 2048 * 64) return;
    const int lane = t & 63, slot = t >> 6;
    const int chk = slot >> 4, w = slot & 15;
    const int tile = w >> 3, limb = (w >> 2) & 1, ksub = w & 3;
    const int q = chk >> 4;
    const int cw = (chk & 15) * 64 + tile * 32 + (lane & 31);
    const int k = ksub * 16 + (lane >> 5) * 8;
    const float* src = cb + ((size_t)q * KS + cw) * DIM + k;
    f16x8 v;
#pragma unroll
    for (int j = 0; j < 8; ++j) {
        float cv = src[j];
        _Float16 hi = (_Float16)cv;
        v[j] = (limb == 0) ? hi : (_Float16)((cv - (float)hi) * RSCALE);
    }
    *(f16x8*)(G + (size_t)chk * CHUNK_H + w * 512 + lane * 8) = v;
}

// ---- pre-pass 2: dc2 seeds written straight into each chunk's tail ----
__global__ void dc2_kernel(const float* __restrict__ cb, float* __restrict__ Gf) {
    int i = blockIdx.x * blockDim.x + threadIdx.x;
    if (i < QS * KS) {
        const float* c = cb + (size_t)i * DIM;
        float s = 0.f;
#pragma unroll
        for (int d = 0; d < DIM; ++d) s = fmaf(c[d], c[d], s);
        const int q = i >> 10, k = i & 1023;
        const int ch = q * 16 + (k >> 6), j = k & 63;
        Gf[(size_t)ch * 4160 + 4096 + j] = -1024.0f * s;
    }
}

// ---- main: 32x32x16 MFMA, 64 tokens/wave as 2 sets of 32, 512 blocks (2/CU).
// Per chunk: 2 cw-tiles x (2 sets x 12-MFMA chain) = 48 MFMAs (half of r6's 96,
// 2x FLOP/instr, 20% faster pipe) at IDENTICAL operand traffic. B layout:
// col(token)=lane&31, k=ksub*16+(lane>>5)*8+j; C/D col=token, row(cw)=
// (reg&3)+8*(reg>>2)+4*(lane>>5) (HW-verified).
__global__ __launch_bounds__(256, 2)
void rvq_mfma_kernel(const float* __restrict__ x,
                     const float* __restrict__ cbf,
                     const _Float16* __restrict__ F,
                     float* __restrict__ out) {
    __shared__ __attribute__((aligned(16))) _Float16 smem[2 * CHUNK_H]; // 33.3 KB

    const int tid  = threadIdx.x;
    const int wave = tid >> 6;
    const int lane = tid & 63;
    const int h    = lane >> 5;     // K-half / row-offset half
    const int col  = lane & 31;     // token within set

    const int tokenBase = blockIdx.x * 256 + wave * 64;

    // token limbs, 2 sets x 4 ksubs (B-frag): th=hi, tl=2048*(r-hi), ts=2048*hi
    f16x8 th00, th01, th02, th03, tl00, tl01, tl02, tl03, ts00, ts01, ts02, ts03;
    f16x8 th10, th11, th12, th13, tl10, tl11, tl12, tl13, ts10, ts11, ts12, ts13;

#define LOADTOK(S, TH0,TH1,TH2,TH3, TL0,TL1,TL2,TL3, TS0,TS1,TS2,TS3) {           \
        const float* xa = x + (size_t)(tokenBase + (S)*32 + col) * DIM + h * 8;   \
        f32x4 a0 = __builtin_nontemporal_load((const f32x4*)(xa));                \
        f32x4 b0 = __builtin_nontemporal_load((const f32x4*)(xa + 4));            \
        f32x4 a1 = __builtin_nontemporal_load((const f32x4*)(xa + 16));           \
        f32x4 b1 = __builtin_nontemporal_load((const f32x4*)(xa + 20));           \
        f32x4 a2 = __builtin_nontemporal_load((const f32x4*)(xa + 32));           \
        f32x4 b2 = __builtin_nontemporal_load((const f32x4*)(xa + 36));           \
        f32x4 a3 = __builtin_nontemporal_load((const f32x4*)(xa + 48));           \
        f32x4 b3 = __builtin_nontemporal_load((const f32x4*)(xa + 52));           \
        _Pragma("unroll")                                                         \
        for (int j = 0; j < 4; ++j) {                                             \
            SPLIT3(a0[j], TH0[j],   TL0[j],   TS0[j]);                            \
            SPLIT3(b0[j], TH0[j+4], TL0[j+4], TS0[j+4]);                          \
            SPLIT3(a1[j], TH1[j],   TL1[j],   TS1[j]);                            \
            SPLIT3(b1[j], TH1[j+4], TL1[j+4], TS1[j+4]);                          \
            SPLIT3(a2[j], TH2[j],   TL2[j],   TS2[j]);                            \
            SPLIT3(b2[j], TH2[j+4], TL2[j+4], TS2[j+4]);                          \
            SPLIT3(a3[j], TH3[j],   TL3[j],   TS3[j]);                            \
            SPLIT3(b3[j], TH3[j+4], TL3[j+4], TS3[j+4]);                          \
        }                                                                         \
    }
    LOADTOK(0, th00,th01,th02,th03, tl00,tl01,tl02,tl03, ts00,ts01,ts02,ts03);
    LOADTOK(1, th10,th11,th12,th13, tl10,tl11,tl12,tl13, ts10,ts11,ts12,ts13);

// stage one full chunk (frags + dc2 tail) of G into LDS buffer BUF.
#define STAGE(GC, BUF) {                                                          \
        const char* _gs = (const char*)F + (size_t)(GC) * CHUNK_B                 \
                          + (wave << 10) + (lane << 4);                           \
        _Float16* _ld = smem + (BUF) * CHUNK_H + (wave << 9);                     \
        _Pragma("unroll")                                                         \
        for (int _j = 0; _j < 4; ++_j)                                            \
            __builtin_amdgcn_global_load_lds(                                     \
                (const __attribute__((address_space(1))) void*)(_gs + _j * 4096), \
                (__attribute__((address_space(3))) void*)(_ld + _j * 2048),       \
                16, 0, 0);                                                        \
        if (wave == 0) {                                                          \
            const char* _gd = (const char*)F + (size_t)(GC) * CHUNK_B + 16384     \
                              + (lane << 2);                                      \
            __builtin_amdgcn_global_load_lds(                                     \
                (const __attribute__((address_space(1))) void*)_gd,               \
                (__attribute__((address_space(3))) void*)(smem + (BUF) * CHUNK_H  \
                                                          + DC2_OFF_H),           \
                4, 0, 0);                                                         \
        }                                                                         \
    }

// One 32-cw tile: seed from dc2 quads, 24 MFMAs (2 sets x depth-12 chain:
// ch*ts + cl*th + ch*tl over 4 K-subtiles), then per-reg argmin (ascending cw).
#define TILE(T, CHI) {                                                             \
        const int tb = (T) * 32;                                                   \
        f32x4 s0 = *(const f32x4*)(dcL + tb +  0 + 4*h);                           \
        f32x4 s1 = *(const f32x4*)(dcL + tb +  8 + 4*h);                           \
        f32x4 s2 = *(const f32x4*)(dcL + tb + 16 + 4*h);                           \
        f32x4 s3 = *(const f32x4*)(dcL + tb + 24 + 4*h);                           \
        f16x8 fh0 = *(const f16x8*)(L + ((T)*8 + 0) * 512);                        \
        f16x8 fh1 = *(const f16x8*)(L + ((T)*8 + 1) * 512);                        \
        f16x8 fh2 = *(const f16x8*)(L + ((T)*8 + 2) * 512);                        \
        f16x8 fh3 = *(const f16x8*)(L + ((T)*8 + 3) * 512);                        \
        f16x8 fl0 = *(const f16x8*)(L + ((T)*8 + 4) * 512);                        \
        f16x8 fl1 = *(const f16x8*)(L + ((T)*8 + 5) * 512);                        \
        f16x8 fl2 = *(const f16x8*)(L + ((T)*8 + 6) * 512);                        \
        f16x8 fl3 = *(const f16x8*)(L + ((T)*8 + 7) * 512);                        \
        f32x16 acc0, acc1;                                                         \
        _Pragma("unroll")                                                          \
        for (int i = 0; i < 4; ++i) {                                              \
            acc0[i] = s0[i]; acc0[i+4] = s1[i];                                    \
            acc0[i+8] = s2[i]; acc0[i+12] = s3[i];                                 \
        }                                                                          \
        acc1 = acc0;                                                               \
        __builtin_amdgcn_s_setprio(1);                                             \
        acc0 = __builtin_amdgcn_mfma_f32_32x32x16_f16(fh0, ts00, acc0, 0,0,0);     \
        acc1 = __builtin_amdgcn_mfma_f32_32x32x16_f16(fh0, ts10, acc1, 0,0,0);     \
        acc0 = __builtin_amdgcn_mfma_f32_32x32x16_f16(fh1, ts01, acc0, 0,0,0);     \
        acc1 = __builtin_amdgcn_mfma_f32_32x32x16_f16(fh1, ts11, acc1, 0,0,0);     \
        acc0 = __builtin_amdgcn_mfma_f32_32x32x16_f16(fh2, ts02, acc0, 0,0,0);     \
        acc1 = __builtin_amdgcn_mfma_f32_32x32x16_f16(fh2, ts12, acc1, 0,0,0);     \
        acc0 = __builtin_amdgcn_mfma_f32_32x32x16_f16(fh3, ts03, acc0, 0,0,0);     \
        acc1 = __builtin_amdgcn_mfma_f32_32x32x16_f16(fh3, ts13, acc1, 0,0,0);     \
        acc0 = __builtin_amdgcn_mfma_f32_32x32x16_f16(fl0, th00, acc0, 0,0,0);     \
        acc1 = __builtin_amdgcn_mfma_f32_32x32x16_f16(fl0, th10, acc1, 0,0,0);     \
        acc0 = __builtin_amdgcn_mfma_f32_32x32x16_f16(fl1, th01, acc0, 0,0,0);     \
        acc1 = __builtin_amdgcn_mfma_f32_32x32x16_f16(fl1, th11, acc1, 0,0,0);     \
        acc0 = __builtin_amdgcn_mfma_f32_32x32x16_f16(fl2, th02, acc0, 0,0,0);     \
        acc1 = __builtin_amdgcn_mfma_f32_32x32x16_f16(fl2, th12, acc1, 0,0,0);     \
        acc0 = __builtin_amdgcn_mfma_f32_32x32x16_f16(fl3, th03, acc0, 0,0,0);     \
        acc1 = __builtin_amdgcn_mfma_f32_32x32x16_f16(fl3, th13, acc1, 0,0,0);     \
        acc0 = __builtin_amdgcn_mfma_f32_32x32x16_f16(fh0, tl00, acc0, 0,0,0);     \
        acc1 = __builtin_amdgcn_mfma_f32_32x32x16_f16(fh0, tl10, acc1, 0,0,0);     \
        acc0 = __builtin_amdgcn_mfma_f32_32x32x16_f16(fh1, tl01, acc0, 0,0,0);     \
        acc1 = __builtin_amdgcn_mfma_f32_32x32x16_f16(fh1, tl11, acc1, 0,0,0);     \
        acc0 = __builtin_amdgcn_mfma_f32_32x32x16_f16(fh2, tl02, acc0, 0,0,0);     \
        acc1 = __builtin_amdgcn_mfma_f32_32x32x16_f16(fh2, tl12, acc1, 0,0,0);     \
        acc0 = __builtin_amdgcn_mfma_f32_32x32x16_f16(fh3, tl03, acc0, 0,0,0);     \
        acc1 = __builtin_amdgcn_mfma_f32_32x32x16_f16(fh3, tl13, acc1, 0,0,0);     \
        __builtin_amdgcn_s_setprio(0);                                             \
        const int cwb = (CHI) * 64 + (T) * 32 + 4 * h;                             \
        _Pragma("unroll")                                                          \
        for (int i = 0; i < 16; ++i) {                                             \
            const int cw = cwb + (i & 3) + 8 * (i >> 2);                           \
            if (acc0[i] > bv0) { bv0 = acc0[i]; bi0 = cw; }                        \
            if (acc1[i] > bv1) { bv1 = acc1[i]; bi1 = cw; }                        \
        }                                                                          \
    }

    // prologue: stage chunk 0 of stage 0
    STAGE(0, 0);
    __syncthreads();
    int cur = 0;

    for (int q = 0; q < QS; ++q) {
        const float* cfq = cbf + (size_t)q * KS * DIM;

        float bv0 = -INFINITY, bv1 = -INFINITY;
        int   bi0 = 0, bi1 = 0;

        for (int ch = 0; ch < 16; ++ch) {
            const int gc = (q << 4) | ch;
            if (gc + 1 < 128) STAGE(gc + 1, cur ^ 1);   // prefetch next chunk

            const _Float16* L   = smem + cur * CHUNK_H + lane * 8;
            const float*    dcL = (const float*)(smem + cur * CHUNK_H + DC2_OFF_H);

            TILE(0, ch);
            TILE(1, ch);

            // barrier doubles as vmcnt/lgkm drain: staged chunk gc+1 resident,
            // all waves done reading buffer cur.
            __syncthreads();
            cur ^= 1;
        }

        // cross-lane merge: lanes l and l+32 hold the same token column with
        // disjoint cw rows -> single shuffle step. Tie-break: lowest index.
        {
            float ov = __shfl_xor(bv0, 32, 64);
            int   oi = __shfl_xor(bi0, 32, 64);
            if (ov > bv0 || (ov == bv0 && oi < bi0)) { bv0 = ov; bi0 = oi; }
            ov = __shfl_xor(bv1, 32, 64);
            oi = __shfl_xor(bi1, 32, 64);
            if (ov > bv1 || (ov == bv1 && oi < bi1)) { bv1 = ov; bi1 = oi; }
        }

        // index writes: lane l writes token tokenBase + l
        {
            const int mybi = (h == 0) ? bi0 : bi1;
            out[(size_t)N_TOK * DIM + (size_t)(tokenBase + lane) * QS + q] = (float)mybi;
        }

        // residual update per set: each lane owns 32 dims (k = s*16 + h*8 + j)
        float ls = 0.f;
#define RES1(CP, OFF, TH, TL, TS) {                                               \
        f32x4 ca = *(const f32x4*)((CP) + (OFF));                                 \
        f32x4 cb2 = *(const f32x4*)((CP) + (OFF) + 4);                            \
        _Pragma("unroll")                                                         \
        for (int j = 0; j < 4; ++j) {                                             \
            float v0 = fmaf(RISCALE, (float)TL[j],   (float)TH[j])   - ca[j];     \
            float v1 = fmaf(RISCALE, (float)TL[j+4], (float)TH[j+4]) - cb2[j];    \
            ls = fmaf(v0, v0, ls); ls = fmaf(v1, v1, ls);                         \
            SPLIT3(v0, TH[j],   TL[j],   TS[j]);                                  \
            SPLIT3(v1, TH[j+4], TL[j+4], TS[j+4]);                                \
        }                                                                         \
    }
        {
            const float* cp = cfq + (size_t)bi0 * DIM + h * 8;
            RES1(cp,  0, th00, tl00, ts00);
            RES1(cp, 16, th01, tl01, ts01);
            RES1(cp, 32, th02, tl02, ts02);
            RES1(cp, 48, th03, tl03, ts03);
        }
        {
            const float* cp = cfq + (size_t)bi1 * DIM + h * 8;
            RES1(cp,  0, th10, tl10, ts10);
            RES1(cp, 16, th11, tl11, ts11);
            RES1(cp, 32, th12, tl12, ts12);
            RES1(cp, 48, th13, tl13, ts13);
        }
#pragma unroll
        for (int mask = 1; mask <= 32; mask <<= 1) ls += __shfl_xor(ls, mask, 64);
        if (lane == 0)
            atomicAdd(out + (size_t)N_TOK * DIM + (size_t)N_TOK * QS + q,
                      ls * (1.0f / ((float)N_TOK * (float)DIM)));
    }

    // xq = x - r_final (reconstruct final residual from limbs), per set
#define XQ1(XB, OB, OFF, TH, TL) {                                                \
        f32x4 a = __builtin_nontemporal_load((const f32x4*)((XB) + (OFF)));       \
        f32x4 b = __builtin_nontemporal_load((const f32x4*)((XB) + (OFF) + 4));   \
        _Pragma("unroll")                                                         \
        for (int j = 0; j < 4; ++j) {                                             \
            a[j] -= fmaf(RISCALE, (float)TL[j],   (float)TH[j]);                  \
            b[j] -= fmaf(RISCALE, (float)TL[j+4], (float)TH[j+4]);                \
        }                                                                         \
        __builtin_nontemporal_store(a, (f32x4*)((OB) + (OFF)));                   \
        __builtin_nontemporal_store(b, (f32x4*)((OB) + (OFF) + 4));               \
    }
    {
        const size_t ra = (size_t)(tokenBase + col) * DIM + h * 8;
        XQ1(x + ra, out + ra,  0, th00, tl00);
        XQ1(x + ra, out + ra, 16, th01, tl01);
        XQ1(x + ra, out + ra, 32, th02, tl02);
        XQ1(x + ra, out + ra, 48, th03, tl03);
    }
    {
        const size_t ra = (size_t)(tokenBase + 32 + col) * DIM + h * 8;
        XQ1(x + ra, out + ra,  0, th10, tl10);
        XQ1(x + ra, out + ra, 16, th11, tl11);
        XQ1(x + ra, out + ra, 32, th12, tl12);
        XQ1(x + ra, out + ra, 48, th13, tl13);
    }
#undef TILE
#undef STAGE
#undef LOADTOK
#undef RES1
#undef XQ1
}

extern "C" void kernel_launch(void* const* d_in, const int* in_sizes, int n_in,
                              void* d_out, int out_size, void* d_ws, size_t ws_size,
                              hipStream_t stream) {
    const float* x   = (const float*)d_in[0];   // (N, D)
    const float* cb  = (const float*)d_in[1];   // (Q, K, D)
    float*       out = (float*)d_out;           // [xq | indices | losses]
    char*        ws  = (char*)d_ws;

    _Float16* G = (_Float16*)ws;   // 128 chunks x 16640 B = 2,129,920 B

    hipMemsetAsync(out + (size_t)N_TOK * DIM + (size_t)N_TOK * QS, 0,
                   QS * sizeof(float), stream);

    conv_kernel<<<512, 256, 0, stream>>>(cb, G);
    dc2_kernel<<<(QS * KS + 255) / 256, 256, 0, stream>>>(cb, (float*)ws);
    rvq_mfma_kernel<<<N_TOK / 256, 256, 0, stream>>>(x, cb, G, out);
}

// Round 8
// 429.042 us; speedup vs baseline: 1.1151x; 1.1151x over previous
//
#include <hip/hip_runtime.h>
#include <math.h>

#define N_TOK 131072
#define DIM   64
#define QS    8
#define KS    1024

typedef _Float16 f16x8 __attribute__((ext_vector_type(8)));
typedef float    f32x4 __attribute__((ext_vector_type(4)));

#define RSCALE   2048.0f
#define RISCALE  4.8828125e-4f   // 2^-11

// split fp32 v into f16 limbs + scaled-hi: v ~= hi + lo*2^-11 ; hs = 2048*hi (exact)
#define SPLIT3(v, hi, lo, hs) { _Float16 _h = (_Float16)(v); (hi) = _h;        \
                                (lo) = (_Float16)(((v) - (float)_h) * RSCALE); \
                                (hs) = (_Float16)((float)_h * RSCALE); }

// ---- workspace layout G: 128 chunks, each 16640 B:
//   [0    .. 16383]  frag limbs: 16 sub-slots of 1KB (4 groups x {h0,h1,l0,l1})
//   [16384.. 16639]  64 floats: -1024*||c||^2 seeds for the chunk's 64 codewords
// Chunk c covers stage q = c>>4, codewords (c&15)*64 .. +63.

// ---- pre-pass 1: codebook -> f16 limbs in MFMA fragment order.
// slot = (q*64+g)*4 + l*2 + h ; chunk c = slot>>4, sub = slot&15.
__global__ void conv_kernel(const float* __restrict__ cb, _Float16* __restrict__ G) {
    int t = blockIdx.x * blockDim.x + threadIdx.x;
    if (t >= 2048 * 64) return;
    const int lane = t & 63, slot = t >> 6;
    const int h = slot & 1, l = (slot >> 1) & 1, g = (slot >> 2) & 63, q = slot >> 8;
    const int cw = g * 16 + (lane & 15);
    const int d0 = h * 32 + (lane >> 4) * 8;
    const float* src = cb + ((size_t)q * KS + cw) * DIM + d0;
    f16x8 v;
#pragma unroll
    for (int j = 0; j < 8; ++j) {
        float c = src[j];
        _Float16 hi = (_Float16)c;
        v[j] = (l == 0) ? hi : (_Float16)((c - (float)hi) * RSCALE);
    }
    const int c = slot >> 4, w = slot & 15;
    *(f16x8*)(G + (size_t)c * 8320 + w * 512 + lane * 8) = v;
}

// ---- pre-pass 2: dc2 seeds written straight into each chunk's tail ----
__global__ void dc2_kernel(const float* __restrict__ cb, float* __restrict__ Gf) {
    int i = blockIdx.x * blockDim.x + threadIdx.x;
    if (i < QS * KS) {
        const float* c = cb + (size_t)i * DIM;
        float s = 0.f;
#pragma unroll
        for (int d = 0; d < DIM; ++d) s = fmaf(c[d], c[d], s);
        const int q = i >> 10, k = i & 1023;
        const int ch = q * 16 + (k >> 6), j = k & 63;
        Gf[(size_t)ch * 4160 + 4096 + j] = -1024.0f * s;
    }
}

#define CHUNK_B   16640     // bytes per chunk (16KB frags + 256B dc2)
#define CHUNK_H   8320      // _Float16 elements per chunk
#define DC2_OFF_H 8192      // half-offset of dc2 region (byte 16384)

// ---- main: r6 structure (4 token-sets/wave, 16x16x32, 392us) with TWO chunks
// per barrier interval (barriers 128 -> 64; pair-staged double buffer, 66.6KB
// dynamic LDS) and s_setprio(1) around each 24-MFMA cluster (T5).
__global__ __launch_bounds__(256, 2)
void rvq_mfma_kernel(const float* __restrict__ x,
                     const float* __restrict__ cbf,
                     const _Float16* __restrict__ F,
                     float* __restrict__ out) {
    extern __shared__ _Float16 smem[];   // 2 buffers x 2 chunks x CHUNK_H = 66560 B

    const int tid  = threadIdx.x;
    const int wave = tid >> 6;
    const int lane = tid & 63;
    const int quad = lane >> 4;
    const int m    = lane & 15;
    const int quad4 = quad * 4;

    const int tokenBase = blockIdx.x * 256 + wave * 64;

    // token limbs, 4 sets (B-frag layout): th = hi, tl = 2048*(r-hi), ts = 2048*hi
    f16x8 th00, th01, tl00, tl01, ts00, ts01;
    f16x8 th10, th11, tl10, tl11, ts10, ts11;
    f16x8 th20, th21, tl20, tl21, ts20, ts21;
    f16x8 th30, th31, tl30, tl31, ts30, ts31;

#define LOADTOK(S, TH0, TH1, TL0, TL1, TS0, TS1) {                                \
        const float* xa = x + (size_t)(tokenBase + (S) * 16 + m) * DIM + quad * 8;\
        f32x4 a0 = __builtin_nontemporal_load((const f32x4*)(xa));                \
        f32x4 a1 = __builtin_nontemporal_load((const f32x4*)(xa + 4));            \
        f32x4 a2 = __builtin_nontemporal_load((const f32x4*)(xa + 32));           \
        f32x4 a3 = __builtin_nontemporal_load((const f32x4*)(xa + 36));           \
        _Pragma("unroll")                                                         \
        for (int j = 0; j < 4; ++j) {                                             \
            SPLIT3(a0[j], TH0[j],   TL0[j],   TS0[j]);                            \
            SPLIT3(a1[j], TH0[j+4], TL0[j+4], TS0[j+4]);                          \
            SPLIT3(a2[j], TH1[j],   TL1[j],   TS1[j]);                            \
            SPLIT3(a3[j], TH1[j+4], TL1[j+4], TS1[j+4]);                          \
        }                                                                         \
    }
    LOADTOK(0, th00, th01, tl00, tl01, ts00, ts01);
    LOADTOK(1, th10, th11, tl10, tl11, ts10, ts11);
    LOADTOK(2, th20, th21, tl20, tl21, ts20, ts21);
    LOADTOK(3, th30, th31, tl30, tl31, ts30, ts31);

// stage chunk GC into pair-buffer BUF, slot J (0/1).
#define STAGE(GC, BUF, J) {                                                       \
        const char* _gs = (const char*)F + (size_t)(GC) * CHUNK_B                 \
                          + (wave << 10) + (lane << 4);                           \
        _Float16* _ld = smem + (BUF) * (2 * CHUNK_H) + (J) * CHUNK_H              \
                        + (wave << 9);                                            \
        _Pragma("unroll")                                                         \
        for (int _j = 0; _j < 4; ++_j)                                            \
            __builtin_amdgcn_global_load_lds(                                     \
                (const __attribute__((address_space(1))) void*)(_gs + _j * 4096), \
                (__attribute__((address_space(3))) void*)(_ld + _j * 2048),       \
                16, 0, 0);                                                        \
        if (wave == 0) {                                                          \
            const char* _gd = (const char*)F + (size_t)(GC) * CHUNK_B + 16384     \
                              + (lane << 2);                                      \
            __builtin_amdgcn_global_load_lds(                                     \
                (const __attribute__((address_space(1))) void*)_gd,               \
                (__attribute__((address_space(3))) void*)(smem                    \
                    + (BUF) * (2 * CHUNK_H) + (J) * CHUNK_H + DC2_OFF_H),         \
                4, 0, 0);                                                         \
        }                                                                         \
    }

// One group: 24 MFMAs = 4 independent depth-6 chains (one per token-set),
// all sharing the same codeword fragments. acc IS the scaled score.
#define COMPUTE(CH0, CH1, CL0, CL1, CIV, G) {                                       \
        __builtin_amdgcn_s_setprio(1);                                              \
        f32x4 A0 = __builtin_amdgcn_mfma_f32_16x16x32_f16(CH0, ts00, CIV, 0,0,0);   \
        f32x4 A1 = __builtin_amdgcn_mfma_f32_16x16x32_f16(CH0, ts10, CIV, 0,0,0);   \
        f32x4 A2 = __builtin_amdgcn_mfma_f32_16x16x32_f16(CH0, ts20, CIV, 0,0,0);   \
        f32x4 A3 = __builtin_amdgcn_mfma_f32_16x16x32_f16(CH0, ts30, CIV, 0,0,0);   \
        A0 = __builtin_amdgcn_mfma_f32_16x16x32_f16(CH1, ts01, A0, 0,0,0);          \
        A1 = __builtin_amdgcn_mfma_f32_16x16x32_f16(CH1, ts11, A1, 0,0,0);          \
        A2 = __builtin_amdgcn_mfma_f32_16x16x32_f16(CH1, ts21, A2, 0,0,0);          \
        A3 = __builtin_amdgcn_mfma_f32_16x16x32_f16(CH1, ts31, A3, 0,0,0);          \
        A0 = __builtin_amdgcn_mfma_f32_16x16x32_f16(CL0, th00, A0, 0,0,0);          \
        A1 = __builtin_amdgcn_mfma_f32_16x16x32_f16(CL0, th10, A1, 0,0,0);          \
        A2 = __builtin_amdgcn_mfma_f32_16x16x32_f16(CL0, th20, A2, 0,0,0);          \
        A3 = __builtin_amdgcn_mfma_f32_16x16x32_f16(CL0, th30, A3, 0,0,0);          \
        A0 = __builtin_amdgcn_mfma_f32_16x16x32_f16(CL1, th01, A0, 0,0,0);          \
        A1 = __builtin_amdgcn_mfma_f32_16x16x32_f16(CL1, th11, A1, 0,0,0);          \
        A2 = __builtin_amdgcn_mfma_f32_16x16x32_f16(CL1, th21, A2, 0,0,0);          \
        A3 = __builtin_amdgcn_mfma_f32_16x16x32_f16(CL1, th31, A3, 0,0,0);          \
        A0 = __builtin_amdgcn_mfma_f32_16x16x32_f16(CH0, tl00, A0, 0,0,0);          \
        A1 = __builtin_amdgcn_mfma_f32_16x16x32_f16(CH0, tl10, A1, 0,0,0);          \
        A2 = __builtin_amdgcn_mfma_f32_16x16x32_f16(CH0, tl20, A2, 0,0,0);          \
        A3 = __builtin_amdgcn_mfma_f32_16x16x32_f16(CH0, tl30, A3, 0,0,0);          \
        A0 = __builtin_amdgcn_mfma_f32_16x16x32_f16(CH1, tl01, A0, 0,0,0);          \
        A1 = __builtin_amdgcn_mfma_f32_16x16x32_f16(CH1, tl11, A1, 0,0,0);          \
        A2 = __builtin_amdgcn_mfma_f32_16x16x32_f16(CH1, tl21, A2, 0,0,0);          \
        A3 = __builtin_amdgcn_mfma_f32_16x16x32_f16(CH1, tl31, A3, 0,0,0);          \
        __builtin_amdgcn_s_setprio(0);                                              \
        const int base = (G) * 16 + quad4;                                          \
        _Pragma("unroll")                                                           \
        for (int i = 0; i < 4; ++i) {                                               \
            if (A0[i] > bv0) { bv0 = A0[i]; bi0 = base + i; }                       \
            if (A1[i] > bv1) { bv1 = A1[i]; bi1 = base + i; }                       \
            if (A2[i] > bv2) { bv2 = A2[i]; bi2 = base + i; }                       \
            if (A3[i] > bv3) { bv3 = A3[i]; bi3 = base + i; }                       \
        }                                                                           \
    }

// one chunk's compute (4 groups), r6 register double-buffer pattern
#define CHUNKBODY(LBASE, GBASE) {                                                 \
        const _Float16* L   = (LBASE) + lane * 8;                                 \
        const float*    dcL = (const float*)((LBASE) + DC2_OFF_H);                \
        f32x4 ci0 = *(const f32x4*)(dcL +  0 + quad4);                            \
        f32x4 ci1 = *(const f32x4*)(dcL + 16 + quad4);                            \
        f32x4 ci2 = *(const f32x4*)(dcL + 32 + quad4);                            \
        f32x4 ci3 = *(const f32x4*)(dcL + 48 + quad4);                            \
        f16x8 g0h0 = *(const f16x8*)(L);                                          \
        f16x8 g0h1 = *(const f16x8*)(L + 512);                                    \
        f16x8 g0l0 = *(const f16x8*)(L + 1024);                                   \
        f16x8 g0l1 = *(const f16x8*)(L + 1536);                                   \
        f16x8 g1h0 = *(const f16x8*)(L + 2048);                                   \
        f16x8 g1h1 = *(const f16x8*)(L + 2560);                                   \
        f16x8 g1l0 = *(const f16x8*)(L + 3072);                                   \
        f16x8 g1l1 = *(const f16x8*)(L + 3584);                                   \
        COMPUTE(g0h0, g0h1, g0l0, g0l1, ci0, (GBASE) + 0);                        \
        g0h0 = *(const f16x8*)(L + 4096);                                         \
        g0h1 = *(const f16x8*)(L + 4608);                                         \
        g0l0 = *(const f16x8*)(L + 5120);                                         \
        g0l1 = *(const f16x8*)(L + 5632);                                         \
        COMPUTE(g1h0, g1h1, g1l0, g1l1, ci1, (GBASE) + 1);                        \
        g1h0 = *(const f16x8*)(L + 6144);                                         \
        g1h1 = *(const f16x8*)(L + 6656);                                         \
        g1l0 = *(const f16x8*)(L + 7168);                                         \
        g1l1 = *(const f16x8*)(L + 7680);                                         \
        COMPUTE(g0h0, g0h1, g0l0, g0l1, ci2, (GBASE) + 2);                        \
        COMPUTE(g1h0, g1h1, g1l0, g1l1, ci3, (GBASE) + 3);                        \
    }

    // prologue: stage pair 0 (chunks 0,1) into buffer 0
    STAGE(0, 0, 0);
    STAGE(1, 0, 1);
    __syncthreads();
    int cur = 0;

    for (int q = 0; q < QS; ++q) {
        const float* cfq = cbf + (size_t)q * KS * DIM;

        float bv0 = -INFINITY, bv1 = -INFINITY, bv2 = -INFINITY, bv3 = -INFINITY;
        int   bi0 = 0, bi1 = 0, bi2 = 0, bi3 = 0;

        for (int p = 0; p < 8; ++p) {
            const int gp = (q << 3) | p;            // global pair 0..63
            if (gp + 1 < 64) {                      // prefetch next pair
                STAGE(2 * gp + 2, cur ^ 1, 0);
                STAGE(2 * gp + 3, cur ^ 1, 1);
            }

            _Float16* base = smem + cur * (2 * CHUNK_H);
            CHUNKBODY(base,           (p * 2 + 0) * 4);
            CHUNKBODY(base + CHUNK_H, (p * 2 + 1) * 4);

            // barrier (with implicit vmcnt/lgkm drain): staged pair gp+1
            // resident; all waves done reading buffer cur.
            __syncthreads();
            cur ^= 1;
        }

        // reduce over the 4 quad-lanes holding the same token (disjoint codewords):
        // 2 shuffle steps. Tie-break: lowest index, matching jnp.argmin.
#define REDUCE(BV, BI) {                                                          \
        _Pragma("unroll")                                                         \
        for (int mask = 16; mask <= 32; mask <<= 1) {                             \
            float ov = __shfl_xor(BV, mask, 64);                                  \
            int   oi = __shfl_xor(BI, mask, 64);                                  \
            if (ov > BV || (ov == BV && oi < BI)) { BV = ov; BI = oi; }           \
        }                                                                         \
    }
        REDUCE(bv0, bi0); REDUCE(bv1, bi1); REDUCE(bv2, bi2); REDUCE(bv3, bi3);

        // index writes: quad s writes set s's token (64 lanes = 64 tokens)
        {
            const int myTok = tokenBase + quad * 16 + m;
            const int mybi  = (quad == 0) ? bi0 : (quad == 1) ? bi1
                            : (quad == 2) ? bi2 : bi3;
            out[(size_t)N_TOK * DIM + (size_t)myTok * QS + q] = (float)mybi;
        }

        // residual update per set: reconstruct r, subtract fp32 codeword, re-split
        float ls = 0.f;
#define RESID(BI, TH0, TH1, TL0, TL1, TS0, TS1) {                                 \
        const float* cp = cfq + (size_t)(BI) * DIM + quad * 8;                    \
        f32x4 c0 = *(const f32x4*)(cp);                                           \
        f32x4 c1 = *(const f32x4*)(cp + 4);                                       \
        f32x4 c2 = *(const f32x4*)(cp + 32);                                      \
        f32x4 c3 = *(const f32x4*)(cp + 36);                                      \
        _Pragma("unroll")                                                         \
        for (int j = 0; j < 4; ++j) {                                             \
            float v0 = fmaf(RISCALE, (float)TL0[j],   (float)TH0[j])   - c0[j];   \
            float v1 = fmaf(RISCALE, (float)TL0[j+4], (float)TH0[j+4]) - c1[j];   \
            float v2 = fmaf(RISCALE, (float)TL1[j],   (float)TH1[j])   - c2[j];   \
            float v3 = fmaf(RISCALE, (float)TL1[j+4], (float)TH1[j+4]) - c3[j];   \
            ls = fmaf(v0, v0, ls); ls = fmaf(v1, v1, ls);                         \
            ls = fmaf(v2, v2, ls); ls = fmaf(v3, v3, ls);                         \
            SPLIT3(v0, TH0[j],   TL0[j],   TS0[j]);                               \
            SPLIT3(v1, TH0[j+4], TL0[j+4], TS0[j+4]);                             \
            SPLIT3(v2, TH1[j],   TL1[j],   TS1[j]);                               \
            SPLIT3(v3, TH1[j+4], TL1[j+4], TS1[j+4]);                             \
        }                                                                         \
    }
        RESID(bi0, th00, th01, tl00, tl01, ts00, ts01);
        RESID(bi1, th10, th11, tl10, tl11, ts10, ts11);
        RESID(bi2, th20, th21, tl20, tl21, ts20, ts21);
        RESID(bi3, th30, th31, tl30, tl31, ts30, ts31);

#pragma unroll
        for (int mask = 1; mask <= 32; mask <<= 1) ls += __shfl_xor(ls, mask, 64);
        if (lane == 0)
            atomicAdd(out + (size_t)N_TOK * DIM + (size_t)N_TOK * QS + q,
                      ls * (1.0f / ((float)N_TOK * (float)DIM)));
    }

    // xq = x - r_final (reconstruct final residual from limbs), per set
#define XQW(S, TH0, TH1, TL0, TL1) {                                              \
        const size_t ra = (size_t)(tokenBase + (S) * 16 + m) * DIM + quad * 8;    \
        f32x4 a0 = __builtin_nontemporal_load((const f32x4*)(x + ra));            \
        f32x4 a1 = __builtin_nontemporal_load((const f32x4*)(x + ra + 4));        \
        f32x4 a2 = __builtin_nontemporal_load((const f32x4*)(x + ra + 32));       \
        f32x4 a3 = __builtin_nontemporal_load((const f32x4*)(x + ra + 36));       \
        _Pragma("unroll")                                                         \
        for (int j = 0; j < 4; ++j) {                                             \
            a0[j] -= fmaf(RISCALE, (float)TL0[j],   (float)TH0[j]);               \
            a1[j] -= fmaf(RISCALE, (float)TL0[j+4], (float)TH0[j+4]);             \
            a2[j] -= fmaf(RISCALE, (float)TL1[j],   (float)TH1[j]);               \
            a3[j] -= fmaf(RISCALE, (float)TL1[j+4], (float)TH1[j+4]);             \
        }                                                                         \
        __builtin_nontemporal_store(a0, (f32x4*)(out + ra));                      \
        __builtin_nontemporal_store(a1, (f32x4*)(out + ra + 4));                  \
        __builtin_nontemporal_store(a2, (f32x4*)(out + ra + 32));                 \
        __builtin_nontemporal_store(a3, (f32x4*)(out + ra + 36));                 \
    }
    XQW(0, th00, th01, tl00, tl01);
    XQW(1, th10, th11, tl10, tl11);
    XQW(2, th20, th21, tl20, tl21);
    XQW(3, th30, th31, tl30, tl31);

#undef COMPUTE
#undef CHUNKBODY
#undef STAGE
#undef LOADTOK
#undef REDUCE
#undef RESID
#undef XQW
}

extern "C" void kernel_launch(void* const* d_in, const int* in_sizes, int n_in,
                              void* d_out, int out_size, void* d_ws, size_t ws_size,
                              hipStream_t stream) {
    const float* x   = (const float*)d_in[0];   // (N, D)
    const float* cb  = (const float*)d_in[1];   // (Q, K, D)
    float*       out = (float*)d_out;           // [xq | indices | losses]
    char*        ws  = (char*)d_ws;

    _Float16* G = (_Float16*)ws;   // 128 chunks x 16640 B = 2,129,920 B

    hipMemsetAsync(out + (size_t)N_TOK * DIM + (size_t)N_TOK * QS, 0,
                   QS * sizeof(float), stream);

    conv_kernel<<<512, 256, 0, stream>>>(cb, G);
    dc2_kernel<<<(QS * KS + 255) / 256, 256, 0, stream>>>(cb, (float*)ws);
    rvq_mfma_kernel<<<N_TOK / 256, 256, 4 * CHUNK_H * sizeof(_Float16), stream>>>(
        x, cb, G, out);
}